// Round 1
// baseline (695.787 us; speedup 1.0000x reference)
//
#include <hip/hip_runtime.h>

#define N_NODES  100000
#define N_EDGES  1000000
#define N_GRAPHS 2048
#define IN_DIM   5
#define HIDDEN   64
#define OUT_DIM  128

// ---------------------------------------------------------------------------
// init: deg=1 (self-loop), pooled sums=0, counts=0
// ---------------------------------------------------------------------------
__global__ void k_init(float* __restrict__ deg, float* __restrict__ sums,
                       float* __restrict__ cnt) {
    int i = blockIdx.x * 256 + threadIdx.x;
    if (i < N_NODES) deg[i] = 1.0f;
    if (i < N_GRAPHS * HIDDEN) sums[i] = 0.0f;
    if (i < N_GRAPHS) cnt[i] = 0.0f;
}

// deg[dst] += 1 over real edges
__global__ void k_deg(const int* __restrict__ dst, float* __restrict__ deg) {
    int e = blockIdx.x * 256 + threadIdx.x;
    if (e < N_EDGES) atomicAdd(&deg[dst[e]], 1.0f);
}

// deg -> dinv = rsqrt(deg)   (deg >= 1 always, so where/max are no-ops)
__global__ void k_dinv(float* __restrict__ deg) {
    int i = blockIdx.x * 256 + threadIdx.x;
    if (i < N_NODES) deg[i] = rsqrtf(deg[i]);
}

// layer-1 linear: t = x @ W1 ;  hs = t*dinv ;  agg(init) = t*dinv^2 (self-loop)
__global__ void k_lin1(const float* __restrict__ x, const float* __restrict__ W1,
                       const float* __restrict__ dinv,
                       float* __restrict__ hs, float* __restrict__ agg) {
    int idx = blockIdx.x * 256 + threadIdx.x;
    if (idx >= N_NODES * HIDDEN) return;
    int i = idx >> 6, f = idx & 63;
    float t = 0.f;
#pragma unroll
    for (int k = 0; k < IN_DIM; k++) t += x[i * IN_DIM + k] * W1[k * HIDDEN + f];
    float d = dinv[i];
    float v = t * d;
    hs[idx]  = v;        // carries dinv[src] factor
    agg[idx] = v * d;    // self-loop: t * dinv^2
}

// scatter: agg[dst,f] += hs[src,f] * dinv[dst]   (64 lanes = 64 features/edge)
__global__ void k_scatter(const int* __restrict__ src, const int* __restrict__ dst,
                          const float* __restrict__ dinv,
                          const float* __restrict__ hs, float* __restrict__ agg) {
    int idx = blockIdx.x * 256 + threadIdx.x;   // max 64M < 2^31
    int e = idx >> 6, f = idx & 63;
    if (e >= N_EDGES) return;
    int s = src[e], d = dst[e];
    float v = hs[s * HIDDEN + f] * dinv[d];
    atomicAdd(&agg[d * HIDDEN + f], v);
}

// h = relu(agg1 + b1); t = h @ W2; hs2 = t*dinv; agg2(init) = t*dinv^2.
// agg2 may alias agg1: each agg1 element is read exactly once, by the thread
// that later writes the same address.
__global__ void k_layer2(const float* __restrict__ agg1, const float* __restrict__ b1,
                         const float* __restrict__ W2, const float* __restrict__ dinv,
                         float* __restrict__ hs2, float* __restrict__ agg2) {
    __shared__ float sh[4][HIDDEN];
    int tid = threadIdx.x;
    int r = tid >> 6, f = tid & 63;
    int node = blockIdx.x * 4 + r;
    float h = 0.f;
    if (node < N_NODES) h = fmaxf(agg1[node * HIDDEN + f] + b1[f], 0.f);
    sh[r][f] = h;
    __syncthreads();
    if (node >= N_NODES) return;
    float t = 0.f;
#pragma unroll 8
    for (int k = 0; k < HIDDEN; k++) t += sh[r][k] * W2[k * HIDDEN + f];
    float d = dinv[node];
    float v = t * d;
    hs2[node * HIDDEN + f]  = v;
    agg2[node * HIDDEN + f] = v * d;
}

// h2 = relu(agg2 + b2); pooled sums/counts via atomics (batch gives graph id)
__global__ void k_pool(const float* __restrict__ agg2, const float* __restrict__ b2,
                       const int* __restrict__ batch,
                       float* __restrict__ sums, float* __restrict__ cnt) {
    int idx = blockIdx.x * 256 + threadIdx.x;
    if (idx >= N_NODES * HIDDEN) return;
    int i = idx >> 6, f = idx & 63;
    int g = batch[i];
    float h = fmaxf(agg2[idx] + b2[f], 0.f);
    atomicAdd(&sums[g * HIDDEN + f], h);
    if (f == 0) atomicAdd(&cnt[g], 1.0f);
}

// per-graph head: pooled = sums/max(cnt,1); z = relu(pooled@W3+b3); out = z@W4+b4
__global__ void k_head(const float* __restrict__ sums, const float* __restrict__ cnt,
                       const float* __restrict__ W3, const float* __restrict__ b3,
                       const float* __restrict__ W4, const float* __restrict__ b4,
                       float* __restrict__ out) {
    __shared__ float p[HIDDEN];
    __shared__ float z[HIDDEN];
    int g = blockIdx.x, tid = threadIdx.x;
    float inv = 1.0f / fmaxf(cnt[g], 1.0f);
    if (tid < HIDDEN) p[tid] = sums[g * HIDDEN + tid] * inv;
    __syncthreads();
    if (tid < HIDDEN) {
        float t = b3[tid];
#pragma unroll 8
        for (int k = 0; k < HIDDEN; k++) t += p[k] * W3[k * HIDDEN + tid];
        z[tid] = fmaxf(t, 0.f);
    }
    __syncthreads();
    float t = b4[tid];
#pragma unroll 8
    for (int k = 0; k < HIDDEN; k++) t += z[k] * W4[k * OUT_DIM + tid];
    out[g * OUT_DIM + tid] = t;
}

extern "C" void kernel_launch(void* const* d_in, const int* in_sizes, int n_in,
                              void* d_out, int out_size, void* d_ws, size_t ws_size,
                              hipStream_t stream) {
    const float* x  = (const float*)d_in[0];
    const int*   ei = (const int*)d_in[1];           // [2, E] flattened
    const int*   batch = (const int*)d_in[2];
    const float* W1 = (const float*)d_in[3];
    const float* b1 = (const float*)d_in[4];
    const float* W2 = (const float*)d_in[5];
    const float* b2 = (const float*)d_in[6];
    const float* W3 = (const float*)d_in[7];
    const float* b3 = (const float*)d_in[8];
    const float* W4 = (const float*)d_in[9];
    const float* b4 = (const float*)d_in[10];
    float* out = (float*)d_out;

    const int* src = ei;
    const int* dst = ei + N_EDGES;

    float* ws   = (float*)d_ws;
    float* dinv = ws;                                  // N_NODES
    float* bufA = dinv + N_NODES;                      // N_NODES*HIDDEN (hs)
    float* bufB = bufA + (size_t)N_NODES * HIDDEN;     // N_NODES*HIDDEN (agg)
    float* sums = bufB + (size_t)N_NODES * HIDDEN;     // N_GRAPHS*HIDDEN
    float* cnt  = sums + (size_t)N_GRAPHS * HIDDEN;    // N_GRAPHS

    const int initN = N_GRAPHS * HIDDEN;               // 131072 > N_NODES
    k_init<<<(initN + 255) / 256, 256, 0, stream>>>(dinv, sums, cnt);
    k_deg<<<(N_EDGES + 255) / 256, 256, 0, stream>>>(dst, dinv);
    k_dinv<<<(N_NODES + 255) / 256, 256, 0, stream>>>(dinv);

    k_lin1<<<(N_NODES * HIDDEN + 255) / 256, 256, 0, stream>>>(x, W1, dinv, bufA, bufB);
    k_scatter<<<(N_EDGES * HIDDEN) / 256, 256, 0, stream>>>(src, dst, dinv, bufA, bufB);

    k_layer2<<<(N_NODES + 3) / 4, 256, 0, stream>>>(bufB, b1, W2, dinv, bufA, bufB);
    k_scatter<<<(N_EDGES * HIDDEN) / 256, 256, 0, stream>>>(src, dst, dinv, bufA, bufB);

    k_pool<<<(N_NODES * HIDDEN + 255) / 256, 256, 0, stream>>>(bufB, b2, batch, sums, cnt);
    k_head<<<N_GRAPHS, 128, 0, stream>>>(sums, cnt, W3, b3, W4, b4, out);
}